// Round 5
// baseline (330.933 us; speedup 1.0000x reference)
//
#include <hip/hip_runtime.h>

typedef __attribute__((ext_vector_type(8)))  short short8;
typedef __attribute__((ext_vector_type(16))) float f32x16;

#define NPTS 2048
#define BATCH 32
#define NUM_CLASSES 6
#define THREADS 256
#define CC 4                 // candidate chunks per (dir,batch)
#define CANDS_BLK 512        // NPTS / CC
#define QC 8                 // query chunks of 256
#define GROUPS 512           // 2 * 32 * 8
#define BF16_ONE ((short)0x3F80)

// ws layout (float index):
//   pmin [GROUPS][CC][256]   at 0            (524288 floats)
//   gpart[GROUPS]            at GPART_OFF    (512 floats)
//   ticks[1 + GROUPS] (int)  at TICK_OFF     (zeroed via memset node each call)
#define GPART_OFF (GROUPS * CC * 256)
#define TICK_OFF  (GPART_OFF + GROUPS)

__device__ __forceinline__ unsigned short f2bf(float x) {
    union { float f; unsigned u; } v; v.f = x;
    unsigned r = v.u + 0x7FFF + ((v.u >> 16) & 1);   // RNE to bf16
    return (unsigned short)(r >> 16);
}
__device__ __forceinline__ float bf2f(unsigned short h) {
    union { unsigned u; float f; } v; v.u = ((unsigned)h) << 16; return v.f;
}

// K-slot plan (K=16): D = a2 + b2 - 2 a.b (hi/lo split, same numerics as R4):
//  k0-2: A=ah  B=-2bh | k3-5: A=al B=-2bh | k6-8: A=ah B=-2bl
//  k9: A=1 B=b2h | k10: A=1 B=b2l | k11: A=a2h B=1 | k12: A=a2l B=1 | k13-15: 0
__global__ __launch_bounds__(THREADS, 4) void chamfer_fused(
    const float* __restrict__ inst, const float* __restrict__ model,
    const float* __restrict__ pred, const int* __restrict__ gt,
    float* __restrict__ ws, float* __restrict__ out)
{
    __shared__ char cands[CANDS_BLK * 32];   // 16 KB
    __shared__ float wsum[4];
    __shared__ int s_tick;

    const int blk   = blockIdx.x;
    const int cc    = blk & 3;
    const int qc    = (blk >> 2) & 7;
    const int batch = (blk >> 5) & 31;
    const int dir   = blk >> 10;
    const int g     = (dir * BATCH + batch) * QC + qc;
    const int tid   = threadIdx.x;
    const int lane  = tid & 63, wid = tid >> 6;
    const int lh    = lane >> 5, lr = lane & 31;

    const float* __restrict__ Q  = dir ? model : inst;
    const float* __restrict__ Cp = dir ? inst  : model;

    // ---- stage this block's 512 candidates into B-frag layout ----
    const float* cb = Cp + ((size_t)batch * NPTS + (size_t)cc * CANDS_BLK) * 3;
    for (int c = tid; c < CANDS_BLK; c += THREADS) {
        float bx = cb[c*3+0], by = cb[c*3+1], bz = cb[c*3+2];
        float m2x = -2.f*bx, m2y = -2.f*by, m2z = -2.f*bz;
        unsigned short hx = f2bf(m2x), hy = f2bf(m2y), hz = f2bf(m2z);
        unsigned short lx = f2bf(m2x - bf2f(hx));
        unsigned short ly = f2bf(m2y - bf2f(hy));
        unsigned short lz = f2bf(m2z - bf2f(hz));
        float b2 = fmaf(bx,bx, fmaf(by,by, bz*bz));
        unsigned short b2h = f2bf(b2);
        unsigned short b2l = f2bf(b2 - bf2f(b2h));
        short8 kg0 = { (short)hx,(short)hy,(short)hz,(short)hx,(short)hy,(short)hz,(short)lx,(short)ly };
        short8 kg1 = { (short)lz,(short)b2h,(short)b2l, BF16_ONE, BF16_ONE, 0,0,0 };
        *(short8*)(cands + c*32)      = kg0;
        *(short8*)(cands + c*32 + 16) = kg1;
    }

    // ---- A-frags (row = lane&31, k = (lane>>5)*8 + j), 64 queries per wave ----
    short8 af[2];
    const float* qb = Q + ((size_t)batch * NPTS + (size_t)qc * 256) * 3;
    #pragma unroll
    for (int qt = 0; qt < 2; ++qt) {
        const int qi = (wid * 2 + qt) * 32 + lr;
        float x = qb[qi*3+0], y = qb[qi*3+1], z = qb[qi*3+2];
        unsigned short hx = f2bf(x), hy = f2bf(y), hz = f2bf(z);
        unsigned short lx = f2bf(x - bf2f(hx));
        unsigned short ly = f2bf(y - bf2f(hy));
        unsigned short lz = f2bf(z - bf2f(hz));
        float a2 = fmaf(x,x, fmaf(y,y, z*z));
        unsigned short a2h = f2bf(a2);
        unsigned short a2l = f2bf(a2 - bf2f(a2h));
        if (lh == 0)
            af[qt] = (short8){ (short)hx,(short)hy,(short)hz,(short)lx,(short)ly,(short)lz,(short)hx,(short)hy };
        else
            af[qt] = (short8){ (short)hz, BF16_ONE, BF16_ONE, (short)a2h,(short)a2l, 0,0,0 };
    }
    __syncthreads();

    // ---- main loop: 16 candidate tiles, 2 mfma each (low VGPR, 4 waves/SIMD) ----
    f32x16 mn, mn2, zero16;
    #pragma unroll
    for (int r = 0; r < 16; ++r) { mn[r] = 3.4e38f; mn2[r] = 3.4e38f; zero16[r] = 0.f; }

    int boff = lr * 32 + lh * 16;
    #pragma unroll 2
    for (int ct = 0; ct < 16; ++ct) {
        short8 b0 = *(const short8*)(cands + boff);
        boff += 1024;
        f32x16 a0 = __builtin_amdgcn_mfma_f32_32x32x16_bf16(af[0], b0, zero16, 0,0,0);
        f32x16 a1 = __builtin_amdgcn_mfma_f32_32x32x16_bf16(af[1], b0, zero16, 0,0,0);
        #pragma unroll
        for (int r = 0; r < 16; ++r) mn[r]  = fminf(mn[r],  a0[r]);
        #pragma unroll
        for (int r = 0; r < 16; ++r) mn2[r] = fminf(mn2[r], a1[r]);
    }

    // ---- epilogue: min across 32 candidate-cols; write per-query chunk mins ----
    // D layout: col = lane&31, row = (reg&3) + 8*(reg>>2) + 4*lh
    float* pmin = ws + (size_t)g * (CC * 256) + cc * 256;
    #pragma unroll
    for (int r = 0; r < 16; ++r) {
        float v = mn[r];
        v = fminf(v, __shfl_xor(v, 1, 64));
        v = fminf(v, __shfl_xor(v, 2, 64));
        v = fminf(v, __shfl_xor(v, 4, 64));
        v = fminf(v, __shfl_xor(v, 8, 64));
        v = fminf(v, __shfl_xor(v, 16, 64));
        if (lr == 0) pmin[(wid*2+0)*32 + ((r&3) + 8*(r>>2) + 4*lh)] = v;
        float w = mn2[r];
        w = fminf(w, __shfl_xor(w, 1, 64));
        w = fminf(w, __shfl_xor(w, 2, 64));
        w = fminf(w, __shfl_xor(w, 4, 64));
        w = fminf(w, __shfl_xor(w, 8, 64));
        w = fminf(w, __shfl_xor(w, 16, 64));
        if (lr == 0) pmin[(wid*2+1)*32 + ((r&3) + 8*(r>>2) + 4*lh)] = w;
    }

    // ---- group ticket: 4th block of (dir,batch,qc) combines chunk mins ----
    int* ticks = (int*)(ws + TICK_OFF);
    __threadfence();
    __syncthreads();                       // all pmin stores drained (vmcnt 0 at barrier)
    if (tid == 0) s_tick = atomicAdd(&ticks[1 + g], 1);
    __syncthreads();
    if (s_tick != CC - 1) return;

    __threadfence();                       // acquire: see other blocks' pmin
    const float* gp = ws + (size_t)g * (CC * 256);
    float v = fminf(fminf(gp[tid], gp[256 + tid]),
                    fminf(gp[512 + tid], gp[768 + tid]));
    #pragma unroll
    for (int o = 32; o > 0; o >>= 1) v += __shfl_down(v, o, 64);
    if (lane == 0) wsum[wid] = v;
    __syncthreads();
    if (tid == 0) {
        ws[GPART_OFF + g] = (wsum[0] + wsum[1]) + (wsum[2] + wsum[3]);
        __threadfence();
        s_tick = atomicAdd(&ticks[0], 1);
    }
    __syncthreads();
    if (s_tick != GROUPS - 1) return;

    // ---- final leader: 512-sum + cross-entropy + output ----
    __threadfence();
    const float* gpart = ws + GPART_OFF;
    float t = gpart[tid] + gpart[tid + 256];
    #pragma unroll
    for (int o = 32; o > 0; o >>= 1) t += __shfl_down(t, o, 64);
    if (lane == 0) wsum[wid] = t;

    __shared__ float s_ce[BATCH];
    if (tid < BATCH) {
        const float* row = pred + tid * NUM_CLASSES;
        float mx = row[0];
        #pragma unroll
        for (int c = 1; c < NUM_CLASSES; ++c) mx = fmaxf(mx, row[c]);
        float se = 0.f;
        #pragma unroll
        for (int c = 0; c < NUM_CLASSES; ++c) se += __expf(row[c] - mx);
        const int lbl = gt[tid];
        s_ce[tid] = -(row[lbl] - mx - __logf(se));
    }
    __syncthreads();

    if (tid == 0) {
        float cd = ((wsum[0] + wsum[1]) + (wsum[2] + wsum[3])) / (float)(BATCH * NPTS);
        float ce = 0.f;
        for (int i = 0; i < BATCH; ++i) ce += s_ce[i];
        ce /= (float)BATCH;
        out[0] = 5.f * cd + ce;
        out[1] = cd;
        out[2] = ce;
    }
}

extern "C" void kernel_launch(void* const* d_in, const int* in_sizes, int n_in,
                              void* d_out, int out_size, void* d_ws, size_t ws_size,
                              hipStream_t stream) {
    const float* inst  = (const float*)d_in[0];
    const float* model = (const float*)d_in[1];
    const float* pred  = (const float*)d_in[2];
    const int*   gt    = (const int*)d_in[3];
    float* out = (float*)d_out;
    float* ws  = (float*)d_ws;

    const size_t need = (size_t)(TICK_OFF + 1 + GROUPS) * sizeof(float) + 64;
    if (ws_size < need) return;   // 256 MB provided; guard only

    // zero the tickets (graph-capturable memset node)
    hipMemsetAsync((char*)d_ws + (size_t)TICK_OFF * sizeof(float), 0,
                   (1 + GROUPS) * sizeof(int), stream);

    chamfer_fused<<<2 * BATCH * QC * CC, THREADS, 0, stream>>>(
        inst, model, pred, gt, ws, out);
}